// Round 1
// baseline (531.621 us; speedup 1.0000x reference)
//
#include <hip/hip_runtime.h>
#include <hip/hip_bf16.h>
#include <math.h>

#define VOLF 100.0f
#define FD 32
#define OUT_DIM 10
#define MAXN 320
#define MAX_LAUNCH_ITERS 8

// ---------------- K1: per-neuron preprocess ----------------
__global__ __launch_bounds__(256) void k_pre(
    const float* __restrict__ positions, const float* __restrict__ radii_in,
    const float* __restrict__ features, float* __restrict__ posx4,
    float* __restrict__ radii, float* __restrict__ e_iw, float* __restrict__ e_ow,
    float* __restrict__ fn, float* __restrict__ scal, int N)
{
    int i = blockIdx.x * blockDim.x + threadIdx.x;
    float my_iw = 0.0f, my_ow = 0.0f, my_r = 0.0f;
    if (i < N) {
        float px = fminf(fmaxf(positions[3*i+0], 0.1f), VOLF - 0.1f);
        float py = fminf(fmaxf(positions[3*i+1], 0.1f), VOLF - 0.1f);
        float pz = fminf(fmaxf(positions[3*i+2], 0.1f), VOLF - 0.1f);
        float sq = px*px + py*py + pz*pz;
        posx4[4*i+0] = px; posx4[4*i+1] = py; posx4[4*i+2] = pz; posx4[4*i+3] = sq;
        float r = fminf(fmaxf(radii_in[i], 1.0f), 50.0f);
        radii[i] = r; my_r = r;
        float xc = fminf(fmaxf(px / VOLF, 0.0f), 1.0f);
        my_iw = expf(-3.0f * xc);
        my_ow = expf(3.0f * (xc - 1.0f));
        e_iw[i] = my_iw; e_ow[i] = my_ow;
        float s = 0.0f;
        #pragma unroll
        for (int k = 0; k < FD; k++) { float v = features[(size_t)i*FD + k]; s += v*v; }
        float nrm = fmaxf(sqrtf(s), 1e-6f);
        #pragma unroll
        for (int k = 0; k < FD; k++) fn[(size_t)i*FD + k] = features[(size_t)i*FD + k] / nrm;
    }
    __shared__ float red[256];
    red[threadIdx.x] = my_iw; __syncthreads();
    for (int s = 128; s > 0; s >>= 1) { if (threadIdx.x < s) red[threadIdx.x] += red[threadIdx.x + s]; __syncthreads(); }
    if (threadIdx.x == 0) atomicAdd(&scal[0], red[0]);
    __syncthreads();
    red[threadIdx.x] = my_ow; __syncthreads();
    for (int s = 128; s > 0; s >>= 1) { if (threadIdx.x < s) red[threadIdx.x] += red[threadIdx.x + s]; __syncthreads(); }
    if (threadIdx.x == 0) atomicAdd(&scal[1], red[0]);
    if (i < N) atomicMax((int*)&scal[2], __float_as_int(my_r));
}

// ---------------- K2: transpose x -> xT [IN][B] ----------------
__global__ __launch_bounds__(256) void k_xt(const float* __restrict__ x, float* __restrict__ xT,
                                            int B, int IN)
{
    int idx = blockIdx.x * blockDim.x + threadIdx.x;
    if (idx < B * IN) {
        int b = idx / IN, k = idx % IN;
        xT[(size_t)k * B + b] = x[idx];
    }
}

// ---------------- K3: act0 = (x @ Win.T) * iw, stored transposed [N][64] ----------------
__global__ __launch_bounds__(256) void k_act0(
    const float* __restrict__ xT, const float* __restrict__ Wi,
    const float* __restrict__ e_iw, const float* __restrict__ scal,
    float* __restrict__ actA, int N, int IN)
{
    int wave = threadIdx.x >> 6, lane = threadIdx.x & 63;
    int i0 = blockIdx.x * 32 + wave * 8;   // 8 neurons per wave, 4 waves per block
    float acc[8] = {0,0,0,0,0,0,0,0};
    for (int k = 0; k < IN; k++) {
        float xv = xT[(size_t)k * 64 + lane];
        #pragma unroll
        for (int n = 0; n < 8; n++)
            acc[n] += xv * Wi[(size_t)(i0 + n) * IN + k];
    }
    float inv = 1.0f / (scal[0] + 1e-6f);
    #pragma unroll
    for (int n = 0; n < 8; n++)
        actA[(size_t)(i0 + n) * 64 + lane] = acc[n] * (e_iw[i0 + n] * inv);
}

// ---------------- K4: build CSR neighbor list ----------------
__global__ __launch_bounds__(256) void k_csr(
    const float* __restrict__ posx4, const float* __restrict__ radii,
    const float* __restrict__ fn, const float* __restrict__ scal,
    int* __restrict__ nbr_idx, float* __restrict__ nbr_w, int* __restrict__ nbr_cnt, int N)
{
    int i = blockIdx.x;
    __shared__ float4 fni4[FD/4];
    __shared__ int cnt;
    if (threadIdx.x == 0) cnt = 0;
    if (threadIdx.x < FD/4) fni4[threadIdx.x] = ((const float4*)(fn + (size_t)i * FD))[threadIdx.x];
    __syncthreads();
    float px = posx4[4*i], py = posx4[4*i+1], pz = posx4[4*i+2], sq = posx4[4*i+3];
    float ri = radii[i];
    float maxr = __int_as_float(((const int*)scal)[2]);
    float inv_ri = 1.0f / (ri + 1e-6f);
    for (int j = threadIdx.x; j < N; j += blockDim.x) {
        float qx = posx4[4*j], qy = posx4[4*j+1], qz = posx4[4*j+2], qs = posx4[4*j+3];
        float d2 = sq + qs - 2.0f * (px*qx + py*qy + pz*qz);
        d2 = fmaxf(d2, 0.0f);
        float dist = (d2 > 0.0f) ? sqrtf(d2) : 0.0f;
        if (dist < maxr) {
            const float4* fnj = (const float4*)(fn + (size_t)j * FD);
            float fs = 0.0f;
            #pragma unroll
            for (int k = 0; k < FD/4; k++) {
                float4 a = fni4[k], b = fnj[k];
                fs += a.x*b.x + a.y*b.y + a.z*b.z + a.w*b.w;
            }
            fs = fminf(fmaxf(fs, -1.0f), 1.0f);
            float w = expf(-fminf(dist * inv_ri, 20.0f)) * (0.3f + 0.7f * fs);
            int pos = atomicAdd(&cnt, 1);
            if (pos < MAXN) {
                nbr_idx[(size_t)i * MAXN + pos] = j;
                nbr_w [(size_t)i * MAXN + pos] = w;
            }
        }
    }
    __syncthreads();
    if (threadIdx.x == 0) nbr_cnt[i] = min(cnt, MAXN);
}

// ---------------- K5: one iteration (sparse matvec over 64 batches) ----------------
__global__ __launch_bounds__(256) void k_iter(
    const float* __restrict__ actIn, float* __restrict__ actOut,
    const int* __restrict__ nbr_idx, const float* __restrict__ nbr_w,
    const int* __restrict__ nbr_cnt, const float* __restrict__ thr,
    const int* __restrict__ nIterPtr, int iterIdx, int N)
{
    int i = blockIdx.x;
    int wave = threadIdx.x >> 6, lane = threadIdx.x & 63;
    if (iterIdx >= *nIterPtr) {
        if (threadIdx.x < 64) actOut[(size_t)i * 64 + threadIdx.x] = actIn[(size_t)i * 64 + threadIdx.x];
        return;
    }
    int cnt = nbr_cnt[i];
    float acc = 0.0f, rs = 0.0f;
    for (int e = wave; e < cnt; e += 4) {
        int j   = nbr_idx[(size_t)i * MAXN + e];
        float w = nbr_w [(size_t)i * MAXN + e];
        rs  += w;
        acc += actIn[(size_t)j * 64 + lane] * w;
    }
    __shared__ float redA[4 * 64];
    __shared__ float redR[4];
    redA[wave * 64 + lane] = acc;
    if (lane == 0) redR[wave] = rs;
    __syncthreads();
    if (wave == 0) {
        float tot = redA[lane] + redA[64 + lane] + redA[128 + lane] + redA[192 + lane];
        float rst = redR[0] + redR[1] + redR[2] + redR[3];
        float v = actIn[(size_t)i * 64 + lane] + tot / (rst + 1e-6f) - thr[i];
        v = fminf(fmaxf(v, 0.0f), 100.0f);
        actOut[(size_t)i * 64 + lane] = v;
    }
}

// ---------------- K6: output projection ----------------
__global__ __launch_bounds__(256) void k_out(
    const float* __restrict__ actF, const float* __restrict__ e_ow,
    const float* __restrict__ scal, const float* __restrict__ outW,
    float* __restrict__ out, int N)
{
    int b = blockIdx.x;
    float acc[OUT_DIM];
    #pragma unroll
    for (int o = 0; o < OUT_DIM; o++) acc[o] = 0.0f;
    float inv = 1.0f / (scal[1] + 1e-6f);
    for (int i = threadIdx.x; i < N; i += blockDim.x) {
        float a = actF[(size_t)i * 64 + b] * (e_ow[i] * inv);
        #pragma unroll
        for (int o = 0; o < OUT_DIM; o++) acc[o] += a * outW[(size_t)i * OUT_DIM + o];
    }
    __shared__ float red[256];
    for (int o = 0; o < OUT_DIM; o++) {
        red[threadIdx.x] = acc[o]; __syncthreads();
        for (int s = 128; s > 0; s >>= 1) { if (threadIdx.x < s) red[threadIdx.x] += red[threadIdx.x + s]; __syncthreads(); }
        if (threadIdx.x == 0) out[b * OUT_DIM + o] = red[0];
        __syncthreads();
    }
}

extern "C" void kernel_launch(void* const* d_in, const int* in_sizes, int n_in,
                              void* d_out, int out_size, void* d_ws, size_t ws_size,
                              hipStream_t stream)
{
    const float* x        = (const float*)d_in[0];
    const float* positions= (const float*)d_in[1];
    const float* Win      = (const float*)d_in[2];
    const float* features = (const float*)d_in[3];
    const float* Wout     = (const float*)d_in[4];
    const float* radii_in = (const float*)d_in[5];
    const float* thr      = (const float*)d_in[6];
    const int*   nIter    = (const int*)  d_in[7];

    const int N  = in_sizes[5];            // 8000
    const int IN = in_sizes[2] / N;        // 784
    const int B  = in_sizes[0] / IN;       // 64 (kernels assume 64 = wave size)
    (void)B;

    float* ws = (float*)d_ws;
    size_t off = 0;
    auto alloc = [&](size_t nfloats) { size_t cur = off; off += (nfloats + 63) & ~(size_t)63; return cur; };
    float* xT      = ws + alloc((size_t)B * IN);
    float* posx4   = ws + alloc((size_t)N * 4);
    float* radii   = ws + alloc(N);
    float* e_iw    = ws + alloc(N);
    float* e_ow    = ws + alloc(N);
    float* scal    = ws + alloc(4);
    float* fn      = ws + alloc((size_t)N * FD);
    float* actA    = ws + alloc((size_t)N * 64);
    float* actB    = ws + alloc((size_t)N * 64);
    float* nbr_w   = ws + alloc((size_t)N * MAXN);
    int*   nbr_idx = (int*)(ws + alloc((size_t)N * MAXN));
    int*   nbr_cnt = (int*)(ws + alloc(N));

    hipMemsetAsync(scal, 0, 4 * sizeof(float), stream);

    k_pre<<<(N + 255) / 256, 256, 0, stream>>>(positions, radii_in, features,
                                               posx4, radii, e_iw, e_ow, fn, scal, N);
    k_xt<<<(B * IN + 255) / 256, 256, 0, stream>>>(x, xT, B, IN);
    k_act0<<<N / 32, 256, 0, stream>>>(xT, Win, e_iw, scal, actA, N, IN);
    k_csr<<<N, 256, 0, stream>>>(posx4, radii, fn, scal, nbr_idx, nbr_w, nbr_cnt, N);

    float* bufs[2] = {actA, actB};
    for (int it = 0; it < MAX_LAUNCH_ITERS; it++) {
        k_iter<<<N, 256, 0, stream>>>(bufs[it & 1], bufs[(it + 1) & 1],
                                      nbr_idx, nbr_w, nbr_cnt, thr, nIter, it, N);
    }
    // after 8 launches result is back in actA
    k_out<<<B, 256, 0, stream>>>(actA, e_ow, scal, Wout, (float*)d_out, N);
}

// Round 2
// 429.651 us; speedup vs baseline: 1.2373x; 1.2373x over previous
//
#include <hip/hip_runtime.h>
#include <hip/hip_bf16.h>
#include <math.h>

#define VOLF 100.0f
#define FD 32
#define OUT_DIM 10
#define MAXN 320
#define MAX_LAUNCH_ITERS 8
#define KSPLIT 4

// ---------------- K1: per-neuron preprocess ----------------
__global__ __launch_bounds__(256) void k_pre(
    const float* __restrict__ positions, const float* __restrict__ radii_in,
    const float* __restrict__ features, float* __restrict__ posx4,
    float* __restrict__ radii, float* __restrict__ e_iw, float* __restrict__ e_ow,
    float* __restrict__ fn, float* __restrict__ scal, int N)
{
    int i = blockIdx.x * blockDim.x + threadIdx.x;
    float my_iw = 0.0f, my_ow = 0.0f, my_r = 0.0f;
    if (i < N) {
        float px = fminf(fmaxf(positions[3*i+0], 0.1f), VOLF - 0.1f);
        float py = fminf(fmaxf(positions[3*i+1], 0.1f), VOLF - 0.1f);
        float pz = fminf(fmaxf(positions[3*i+2], 0.1f), VOLF - 0.1f);
        float sq = px*px + py*py + pz*pz;
        posx4[4*i+0] = px; posx4[4*i+1] = py; posx4[4*i+2] = pz; posx4[4*i+3] = sq;
        float r = fminf(fmaxf(radii_in[i], 1.0f), 50.0f);
        radii[i] = r; my_r = r;
        float xc = fminf(fmaxf(px / VOLF, 0.0f), 1.0f);
        my_iw = expf(-3.0f * xc);
        my_ow = expf(3.0f * (xc - 1.0f));
        e_iw[i] = my_iw; e_ow[i] = my_ow;
        float s = 0.0f;
        #pragma unroll
        for (int k = 0; k < FD; k++) { float v = features[(size_t)i*FD + k]; s += v*v; }
        float nrm = fmaxf(sqrtf(s), 1e-6f);
        #pragma unroll
        for (int k = 0; k < FD; k++) fn[(size_t)i*FD + k] = features[(size_t)i*FD + k] / nrm;
    }
    __shared__ float red[256];
    red[threadIdx.x] = my_iw; __syncthreads();
    for (int s = 128; s > 0; s >>= 1) { if (threadIdx.x < s) red[threadIdx.x] += red[threadIdx.x + s]; __syncthreads(); }
    if (threadIdx.x == 0) atomicAdd(&scal[0], red[0]);
    __syncthreads();
    red[threadIdx.x] = my_ow; __syncthreads();
    for (int s = 128; s > 0; s >>= 1) { if (threadIdx.x < s) red[threadIdx.x] += red[threadIdx.x + s]; __syncthreads(); }
    if (threadIdx.x == 0) atomicAdd(&scal[1], red[0]);
    if (i < N) atomicMax((int*)&scal[2], __float_as_int(my_r));
}

// ---------------- K2: transpose x -> xT [IN][B] ----------------
__global__ __launch_bounds__(256) void k_xt(const float* __restrict__ x, float* __restrict__ xT,
                                            int B, int IN)
{
    int idx = blockIdx.x * blockDim.x + threadIdx.x;
    if (idx < B * IN) {
        int b = idx / IN, k = idx % IN;
        xT[(size_t)k * B + b] = x[idx];
    }
}

// ---------------- K3: partial act0 = x @ Win.T (K-split), stored [ks][N][64] ----------------
__global__ __launch_bounds__(256) void k_act0(
    const float* __restrict__ xT, const float* __restrict__ Wi,
    float* __restrict__ partial, int N, int IN)
{
    int wave = threadIdx.x >> 6, lane = threadIdx.x & 63;
    int i0 = blockIdx.x * 32 + wave * 8;   // 8 neurons per wave, 4 waves per block
    int kchunk = IN / KSPLIT;              // 196
    int k0 = blockIdx.y * kchunk;
    int k1 = k0 + kchunk;
    float acc[8] = {0,0,0,0,0,0,0,0};
    for (int k = k0; k < k1; k += 4) {
        float xv0 = xT[(size_t)(k+0) * 64 + lane];
        float xv1 = xT[(size_t)(k+1) * 64 + lane];
        float xv2 = xT[(size_t)(k+2) * 64 + lane];
        float xv3 = xT[(size_t)(k+3) * 64 + lane];
        #pragma unroll
        for (int n = 0; n < 8; n++) {
            const float4 w = *(const float4*)(Wi + (size_t)(i0 + n) * IN + k);
            acc[n] += w.x * xv0 + w.y * xv1 + w.z * xv2 + w.w * xv3;
        }
    }
    #pragma unroll
    for (int n = 0; n < 8; n++)
        partial[((size_t)blockIdx.y * N + (i0 + n)) * 64 + lane] = acc[n];
}

// ---------------- K3b: reduce K-split partials, apply input gating ----------------
__global__ __launch_bounds__(256) void k_act0_red(
    const float* __restrict__ partial, const float* __restrict__ e_iw,
    const float* __restrict__ scal, float* __restrict__ actA, int N)
{
    int idx = blockIdx.x * 256 + threadIdx.x;   // over N*64
    int i = idx >> 6;
    size_t stride = (size_t)N * 64;
    float s = partial[idx] + partial[stride + idx] + partial[2*stride + idx] + partial[3*stride + idx];
    float inv = 1.0f / (scal[0] + 1e-6f);
    actA[idx] = s * (e_iw[i] * inv);
}

// ---------------- K4: build CSR neighbor list (4 neurons per block) + row inverse ----------------
__global__ __launch_bounds__(256) void k_csr(
    const float* __restrict__ posx4, const float* __restrict__ radii,
    const float* __restrict__ fn, const float* __restrict__ scal,
    int* __restrict__ nbr_idx, float* __restrict__ nbr_w, int* __restrict__ nbr_cnt,
    float* __restrict__ rowinv, int N)
{
    int i0 = blockIdx.x * 4;
    __shared__ float fni[4][FD];
    __shared__ int cnt[4];
    __shared__ float red[256];
    if (threadIdx.x < 4) cnt[threadIdx.x] = 0;
    if (threadIdx.x < 4 * FD / 4)
        ((float4*)&fni[0][0])[threadIdx.x] = ((const float4*)(fn + (size_t)i0 * FD))[threadIdx.x];
    __syncthreads();
    float pix[4], piy[4], piz[4], pis[4], invr[4];
    #pragma unroll
    for (int t = 0; t < 4; t++) {
        pix[t] = posx4[4*(i0+t)+0]; piy[t] = posx4[4*(i0+t)+1];
        piz[t] = posx4[4*(i0+t)+2]; pis[t] = posx4[4*(i0+t)+3];
        invr[t] = 1.0f / (radii[i0+t] + 1e-6f);
    }
    float maxr = __int_as_float(((const int*)scal)[2]);
    for (int j = threadIdx.x; j < N; j += 256) {
        float4 pj = ((const float4*)posx4)[j];
        #pragma unroll
        for (int t = 0; t < 4; t++) {
            float d2 = fmaxf(pis[t] + pj.w - 2.0f*(pix[t]*pj.x + piy[t]*pj.y + piz[t]*pj.z), 0.0f);
            float dist = (d2 > 0.0f) ? sqrtf(d2) : 0.0f;
            if (dist < maxr) {
                const float4* fnj = (const float4*)(fn + (size_t)j * FD);
                float fs = 0.0f;
                #pragma unroll
                for (int k = 0; k < FD/4; k++) {
                    float4 a = ((const float4*)fni[t])[k], b = fnj[k];
                    fs += a.x*b.x + a.y*b.y + a.z*b.z + a.w*b.w;
                }
                fs = fminf(fmaxf(fs, -1.0f), 1.0f);
                float w = expf(-fminf(dist * invr[t], 20.0f)) * (0.3f + 0.7f * fs);
                int pos = atomicAdd(&cnt[t], 1);
                if (pos < MAXN) {
                    nbr_idx[(size_t)(i0+t) * MAXN + pos] = j;
                    nbr_w [(size_t)(i0+t) * MAXN + pos] = w;
                }
            }
        }
    }
    __syncthreads();
    for (int t = 0; t < 4; t++) {
        int c = min(cnt[t], MAXN);
        float s = 0.0f;
        for (int e = threadIdx.x; e < c; e += 256) s += nbr_w[(size_t)(i0+t) * MAXN + e];
        red[threadIdx.x] = s; __syncthreads();
        for (int st = 128; st > 0; st >>= 1) { if (threadIdx.x < st) red[threadIdx.x] += red[threadIdx.x + st]; __syncthreads(); }
        if (threadIdx.x == 0) { nbr_cnt[i0+t] = c; rowinv[i0+t] = 1.0f / (red[0] + 1e-6f); }
        __syncthreads();
    }
}

// ---------------- K5: one iteration (sparse matvec over 64 batches) ----------------
__global__ __launch_bounds__(256) void k_iter(
    const float* __restrict__ actIn, float* __restrict__ actOut,
    const int* __restrict__ nbr_idx, const float* __restrict__ nbr_w,
    const int* __restrict__ nbr_cnt, const float* __restrict__ rowinv,
    const float* __restrict__ thr,
    const int* __restrict__ nIterPtr, int iterIdx, int N)
{
    if (iterIdx >= min(*nIterPtr, MAX_LAUNCH_ITERS)) return;   // inactive launch: no-op
    int i = blockIdx.x;
    int wave = threadIdx.x >> 6, lane = threadIdx.x & 63;
    int cnt = nbr_cnt[i];
    float acc = 0.0f;
    for (int e = wave; e < cnt; e += 4) {
        int j   = nbr_idx[(size_t)i * MAXN + e];
        float w = nbr_w [(size_t)i * MAXN + e];
        acc += actIn[(size_t)j * 64 + lane] * w;
    }
    __shared__ float redA[4 * 64];
    redA[wave * 64 + lane] = acc;
    __syncthreads();
    if (wave == 0) {
        float tot = redA[lane] + redA[64 + lane] + redA[128 + lane] + redA[192 + lane];
        float v = actIn[(size_t)i * 64 + lane] + tot * rowinv[i] - thr[i];
        v = fminf(fmaxf(v, 0.0f), 100.0f);
        actOut[(size_t)i * 64 + lane] = v;
    }
}

// ---------------- K6: output projection (runtime buffer select) ----------------
__global__ __launch_bounds__(256) void k_out(
    const float* __restrict__ actA, const float* __restrict__ actB,
    const int* __restrict__ nIterPtr, const float* __restrict__ e_ow,
    const float* __restrict__ scal, const float* __restrict__ outW,
    float* __restrict__ out, int N)
{
    int m = min(*nIterPtr, MAX_LAUNCH_ITERS);
    const float* actF = (m & 1) ? actB : actA;
    int b = blockIdx.x;
    float acc[OUT_DIM];
    #pragma unroll
    for (int o = 0; o < OUT_DIM; o++) acc[o] = 0.0f;
    float inv = 1.0f / (scal[1] + 1e-6f);
    for (int i = threadIdx.x; i < N; i += blockDim.x) {
        float a = actF[(size_t)i * 64 + b] * (e_ow[i] * inv);
        #pragma unroll
        for (int o = 0; o < OUT_DIM; o++) acc[o] += a * outW[(size_t)i * OUT_DIM + o];
    }
    __shared__ float red[256];
    for (int o = 0; o < OUT_DIM; o++) {
        red[threadIdx.x] = acc[o]; __syncthreads();
        for (int s = 128; s > 0; s >>= 1) { if (threadIdx.x < s) red[threadIdx.x] += red[threadIdx.x + s]; __syncthreads(); }
        if (threadIdx.x == 0) out[b * OUT_DIM + o] = red[0];
        __syncthreads();
    }
}

extern "C" void kernel_launch(void* const* d_in, const int* in_sizes, int n_in,
                              void* d_out, int out_size, void* d_ws, size_t ws_size,
                              hipStream_t stream)
{
    const float* x        = (const float*)d_in[0];
    const float* positions= (const float*)d_in[1];
    const float* Win      = (const float*)d_in[2];
    const float* features = (const float*)d_in[3];
    const float* Wout     = (const float*)d_in[4];
    const float* radii_in = (const float*)d_in[5];
    const float* thr      = (const float*)d_in[6];
    const int*   nIter    = (const int*)  d_in[7];

    const int N  = in_sizes[5];            // 8000
    const int IN = in_sizes[2] / N;        // 784
    const int B  = in_sizes[0] / IN;       // 64 (kernels assume 64 = wave size)
    (void)B;

    float* ws = (float*)d_ws;
    size_t off = 0;
    auto alloc = [&](size_t nfloats) { size_t cur = off; off += (nfloats + 63) & ~(size_t)63; return cur; };
    float* xT      = ws + alloc((size_t)B * IN);
    float* posx4   = ws + alloc((size_t)N * 4);
    float* radii   = ws + alloc(N);
    float* e_iw    = ws + alloc(N);
    float* e_ow    = ws + alloc(N);
    float* rowinv  = ws + alloc(N);
    float* scal    = ws + alloc(4);
    float* fn      = ws + alloc((size_t)N * FD);
    float* actA    = ws + alloc((size_t)N * 64);
    float* actB    = ws + alloc((size_t)N * 64);
    float* nbr_w   = ws + alloc((size_t)N * MAXN);
    int*   nbr_idx = (int*)(ws + alloc((size_t)N * MAXN));
    int*   nbr_cnt = (int*)(ws + alloc(N));
    // partial act0 [KSPLIT][N][64] aliased onto nbr_w/nbr_idx (consumed before k_csr writes them)
    float* partial = nbr_w;   // needs KSPLIT*N*64 = 2.048M floats <= N*MAXN = 2.56M floats

    hipMemsetAsync(scal, 0, 4 * sizeof(float), stream);

    k_pre<<<(N + 255) / 256, 256, 0, stream>>>(positions, radii_in, features,
                                               posx4, radii, e_iw, e_ow, fn, scal, N);
    k_xt<<<(B * IN + 255) / 256, 256, 0, stream>>>(x, xT, B, IN);
    k_act0<<<dim3(N / 32, KSPLIT), 256, 0, stream>>>(xT, Win, partial, N, IN);
    k_act0_red<<<(N * 64) / 256, 256, 0, stream>>>(partial, e_iw, scal, actA, N);
    k_csr<<<N / 4, 256, 0, stream>>>(posx4, radii, fn, scal, nbr_idx, nbr_w, nbr_cnt, rowinv, N);

    float* bufs[2] = {actA, actB};
    for (int it = 0; it < MAX_LAUNCH_ITERS; it++) {
        k_iter<<<N, 256, 0, stream>>>(bufs[it & 1], bufs[(it + 1) & 1],
                                      nbr_idx, nbr_w, nbr_cnt, rowinv, thr, nIter, it, N);
    }
    k_out<<<B, 256, 0, stream>>>(actA, actB, nIter, e_ow, scal, Wout, (float*)d_out, N);
}

// Round 3
// 296.186 us; speedup vs baseline: 1.7949x; 1.4506x over previous
//
#include <hip/hip_runtime.h>
#include <hip/hip_bf16.h>
#include <math.h>

#define VOLF 100.0f
#define FD 32
#define OUT_DIM 10
#define MAXN 320
#define MAX_LAUNCH_ITERS 4
#define KSPLIT 7
#define ITILE 8
#define OB 128   // k_out partial blocks

// ---------------- K1: per-neuron preprocess ----------------
__global__ __launch_bounds__(256) void k_pre(
    const float* __restrict__ positions, const float* __restrict__ radii_in,
    const float* __restrict__ features, float* __restrict__ posx4,
    float* __restrict__ radii, float* __restrict__ e_iw, float* __restrict__ e_ow,
    float* __restrict__ fn, float* __restrict__ scal, int N)
{
    int i = blockIdx.x * blockDim.x + threadIdx.x;
    float my_iw = 0.0f, my_ow = 0.0f, my_r = 0.0f;
    if (i < N) {
        float px = fminf(fmaxf(positions[3*i+0], 0.1f), VOLF - 0.1f);
        float py = fminf(fmaxf(positions[3*i+1], 0.1f), VOLF - 0.1f);
        float pz = fminf(fmaxf(positions[3*i+2], 0.1f), VOLF - 0.1f);
        float sq = px*px + py*py + pz*pz;
        posx4[4*i+0] = px; posx4[4*i+1] = py; posx4[4*i+2] = pz; posx4[4*i+3] = sq;
        float r = fminf(fmaxf(radii_in[i], 1.0f), 50.0f);
        radii[i] = r; my_r = r;
        float xc = fminf(fmaxf(px / VOLF, 0.0f), 1.0f);
        my_iw = expf(-3.0f * xc);
        my_ow = expf(3.0f * (xc - 1.0f));
        e_iw[i] = my_iw; e_ow[i] = my_ow;
        float s = 0.0f;
        #pragma unroll
        for (int k = 0; k < FD; k++) { float v = features[(size_t)i*FD + k]; s += v*v; }
        float nrm = fmaxf(sqrtf(s), 1e-6f);
        #pragma unroll
        for (int k = 0; k < FD; k++) fn[(size_t)i*FD + k] = features[(size_t)i*FD + k] / nrm;
    }
    __shared__ float red[256];
    red[threadIdx.x] = my_iw; __syncthreads();
    for (int s = 128; s > 0; s >>= 1) { if (threadIdx.x < s) red[threadIdx.x] += red[threadIdx.x + s]; __syncthreads(); }
    if (threadIdx.x == 0) atomicAdd(&scal[0], red[0]);
    __syncthreads();
    red[threadIdx.x] = my_ow; __syncthreads();
    for (int s = 128; s > 0; s >>= 1) { if (threadIdx.x < s) red[threadIdx.x] += red[threadIdx.x + s]; __syncthreads(); }
    if (threadIdx.x == 0) atomicAdd(&scal[1], red[0]);
    if (i < N) atomicMax((int*)&scal[2], __float_as_int(my_r));
}

// ---------------- K2: transpose x -> xT [IN][B] ----------------
__global__ __launch_bounds__(256) void k_xt(const float* __restrict__ x, float* __restrict__ xT,
                                            int B, int IN)
{
    int idx = blockIdx.x * blockDim.x + threadIdx.x;
    if (idx < B * IN) {
        int b = idx / IN, k = idx % IN;
        xT[(size_t)k * B + b] = x[idx];
    }
}

// ---------------- K3: partial act0 = x @ Win.T (K-split), stored [ks][N][64] ----------------
__global__ __launch_bounds__(256) void k_act0(
    const float* __restrict__ xT, const float* __restrict__ Wi,
    float* __restrict__ partial, int N, int IN)
{
    int wave = threadIdx.x >> 6, lane = threadIdx.x & 63;
    int i0 = blockIdx.x * 32 + wave * 8;   // 8 neurons per wave, 4 waves per block
    int kchunk = IN / KSPLIT;              // 112
    int k0 = blockIdx.y * kchunk;
    int k1 = k0 + kchunk;
    float acc[8] = {0,0,0,0,0,0,0,0};
    for (int k = k0; k < k1; k += 4) {
        float xv0 = xT[(size_t)(k+0) * 64 + lane];
        float xv1 = xT[(size_t)(k+1) * 64 + lane];
        float xv2 = xT[(size_t)(k+2) * 64 + lane];
        float xv3 = xT[(size_t)(k+3) * 64 + lane];
        #pragma unroll
        for (int n = 0; n < 8; n++) {
            const float4 w = *(const float4*)(Wi + (size_t)(i0 + n) * IN + k);
            acc[n] += w.x * xv0 + w.y * xv1 + w.z * xv2 + w.w * xv3;
        }
    }
    #pragma unroll
    for (int n = 0; n < 8; n++)
        partial[((size_t)blockIdx.y * N + (i0 + n)) * 64 + lane] = acc[n];
}

// ---------------- K3b: reduce K-split partials, apply input gating ----------------
__global__ __launch_bounds__(256) void k_act0_red(
    const float* __restrict__ partial, const float* __restrict__ e_iw,
    const float* __restrict__ scal, float* __restrict__ actA, int N)
{
    int idx = blockIdx.x * 256 + threadIdx.x;   // over N*64
    int i = idx >> 6;
    size_t stride = (size_t)N * 64;
    float s = 0.0f;
    #pragma unroll
    for (int ks = 0; ks < KSPLIT; ks++) s += partial[ks * stride + idx];
    float inv = 1.0f / (scal[0] + 1e-6f);
    actA[idx] = s * (e_iw[i] * inv);
}

// ---------------- K4a: dense distance scan -> compacted (j, dist) ----------------
__global__ __launch_bounds__(256) void k_scan(
    const float* __restrict__ posx4, const float* __restrict__ scal,
    int* __restrict__ nbr_idx, float* __restrict__ nbr_w /* dist out */,
    int* __restrict__ nbr_cnt, int N)
{
    int i0 = blockIdx.x * ITILE;
    __shared__ int cnt[ITILE];
    if (threadIdx.x < ITILE) cnt[threadIdx.x] = 0;
    __syncthreads();
    float4 pi[ITILE];
    #pragma unroll
    for (int t = 0; t < ITILE; t++) pi[t] = ((const float4*)posx4)[i0 + t];
    float maxr = __int_as_float(((const int*)scal)[2]);
    for (int j = threadIdx.x; j < N; j += 256) {
        float4 pj = ((const float4*)posx4)[j];
        #pragma unroll
        for (int t = 0; t < ITILE; t++) {
            float d2 = fmaxf(pi[t].w + pj.w - 2.0f*(pi[t].x*pj.x + pi[t].y*pj.y + pi[t].z*pj.z), 0.0f);
            float dist = (d2 > 0.0f) ? sqrtf(d2) : 0.0f;
            if (dist < maxr) {
                int pos = atomicAdd(&cnt[t], 1);
                if (pos < MAXN) {
                    nbr_idx[(size_t)(i0+t) * MAXN + pos] = j;
                    nbr_w [(size_t)(i0+t) * MAXN + pos] = dist;
                }
            }
        }
    }
    __syncthreads();
    if (threadIdx.x < ITILE) nbr_cnt[i0 + threadIdx.x] = min(cnt[threadIdx.x], MAXN);
}

// ---------------- K4b: dense weight computation over compacted edges ----------------
__global__ __launch_bounds__(128) void k_weight(
    const float* __restrict__ fn, const float* __restrict__ radii,
    const int* __restrict__ nbr_idx, float* __restrict__ nbr_w /* in: dist, out: w */,
    const int* __restrict__ nbr_cnt, float* __restrict__ rowinv, int N)
{
    int i = blockIdx.x;
    __shared__ float4 fni[FD/4];
    __shared__ float red[128];
    if (threadIdx.x < FD/4) fni[threadIdx.x] = ((const float4*)(fn + (size_t)i * FD))[threadIdx.x];
    __syncthreads();
    float inv_ri = 1.0f / (radii[i] + 1e-6f);
    int cnt = nbr_cnt[i];
    float s = 0.0f;
    for (int e = threadIdx.x; e < cnt; e += 128) {
        int j     = nbr_idx[(size_t)i * MAXN + e];
        float dist= nbr_w [(size_t)i * MAXN + e];
        const float4* fnj = (const float4*)(fn + (size_t)j * FD);
        float fs = 0.0f;
        #pragma unroll
        for (int k = 0; k < FD/4; k++) {
            float4 a = fni[k], b = fnj[k];
            fs += a.x*b.x + a.y*b.y + a.z*b.z + a.w*b.w;
        }
        fs = fminf(fmaxf(fs, -1.0f), 1.0f);
        float w = expf(-fminf(dist * inv_ri, 20.0f)) * (0.3f + 0.7f * fs);
        nbr_w[(size_t)i * MAXN + e] = w;
        s += w;
    }
    red[threadIdx.x] = s; __syncthreads();
    for (int st = 64; st > 0; st >>= 1) { if (threadIdx.x < st) red[threadIdx.x] += red[threadIdx.x + st]; __syncthreads(); }
    if (threadIdx.x == 0) rowinv[i] = 1.0f / (red[0] + 1e-6f);
}

// ---------------- K5: one iteration (sparse matvec over 64 batches) ----------------
__global__ __launch_bounds__(256) void k_iter(
    const float* __restrict__ actIn, float* __restrict__ actOut,
    const int* __restrict__ nbr_idx, const float* __restrict__ nbr_w,
    const int* __restrict__ nbr_cnt, const float* __restrict__ rowinv,
    const float* __restrict__ thr,
    const int* __restrict__ nIterPtr, int iterIdx, int N)
{
    if (iterIdx >= min(*nIterPtr, MAX_LAUNCH_ITERS)) return;   // inactive launch: no-op
    int i = blockIdx.x;
    int wave = threadIdx.x >> 6, lane = threadIdx.x & 63;
    int cnt = nbr_cnt[i];
    float acc = 0.0f;
    for (int e = wave; e < cnt; e += 4) {
        int j   = nbr_idx[(size_t)i * MAXN + e];
        float w = nbr_w [(size_t)i * MAXN + e];
        acc += actIn[(size_t)j * 64 + lane] * w;
    }
    __shared__ float redA[4 * 64];
    redA[wave * 64 + lane] = acc;
    __syncthreads();
    if (wave == 0) {
        float tot = redA[lane] + redA[64 + lane] + redA[128 + lane] + redA[192 + lane];
        float v = actIn[(size_t)i * 64 + lane] + tot * rowinv[i] - thr[i];
        v = fminf(fmaxf(v, 0.0f), 100.0f);
        actOut[(size_t)i * 64 + lane] = v;
    }
}

// ---------------- K6a: output projection partials ----------------
__global__ __launch_bounds__(256) void k_out1(
    const float* __restrict__ actA, const float* __restrict__ actB,
    const int* __restrict__ nIterPtr, const float* __restrict__ e_ow,
    const float* __restrict__ scal, const float* __restrict__ outW,
    float* __restrict__ outPart, int N)
{
    int m = min(*nIterPtr, MAX_LAUNCH_ITERS);
    const float* actF = (m & 1) ? actB : actA;
    int wave = threadIdx.x >> 6, lane = threadIdx.x & 63;
    float inv = 1.0f / (scal[1] + 1e-6f);
    float acc[OUT_DIM];
    #pragma unroll
    for (int o = 0; o < OUT_DIM; o++) acc[o] = 0.0f;
    for (int i = blockIdx.x * 4 + wave; i < N; i += OB * 4) {
        float a = actF[(size_t)i * 64 + lane] * (e_ow[i] * inv);
        const float* wo = outW + (size_t)i * OUT_DIM;
        #pragma unroll
        for (int o = 0; o < OUT_DIM; o++) acc[o] += a * wo[o];
    }
    __shared__ float red[4][OUT_DIM][64];
    #pragma unroll
    for (int o = 0; o < OUT_DIM; o++) red[wave][o][lane] = acc[o];
    __syncthreads();
    if (wave == 0) {
        #pragma unroll
        for (int o = 0; o < OUT_DIM; o++) {
            float s = red[0][o][lane] + red[1][o][lane] + red[2][o][lane] + red[3][o][lane];
            outPart[((size_t)blockIdx.x * OUT_DIM + o) * 64 + lane] = s;
        }
    }
}

// ---------------- K6b: reduce partials -> out[b*10+o] ----------------
__global__ __launch_bounds__(256) void k_out2(
    const float* __restrict__ outPart, float* __restrict__ out)
{
    int t = blockIdx.x * 256 + threadIdx.x;     // over 640
    if (t >= 64 * OUT_DIM) return;
    int b = t / OUT_DIM, o = t % OUT_DIM;
    float s = 0.0f;
    for (int blk = 0; blk < OB; blk++)
        s += outPart[((size_t)blk * OUT_DIM + o) * 64 + b];
    out[t] = s;
}

extern "C" void kernel_launch(void* const* d_in, const int* in_sizes, int n_in,
                              void* d_out, int out_size, void* d_ws, size_t ws_size,
                              hipStream_t stream)
{
    const float* x        = (const float*)d_in[0];
    const float* positions= (const float*)d_in[1];
    const float* Win      = (const float*)d_in[2];
    const float* features = (const float*)d_in[3];
    const float* Wout     = (const float*)d_in[4];
    const float* radii_in = (const float*)d_in[5];
    const float* thr      = (const float*)d_in[6];
    const int*   nIter    = (const int*)  d_in[7];

    const int N  = in_sizes[5];            // 8000
    const int IN = in_sizes[2] / N;        // 784
    const int B  = in_sizes[0] / IN;       // 64 (kernels assume 64 = wave size)
    (void)B;

    float* ws = (float*)d_ws;
    size_t off = 0;
    auto alloc = [&](size_t nfloats) { size_t cur = off; off += (nfloats + 63) & ~(size_t)63; return cur; };
    float* xT      = ws + alloc((size_t)B * IN);
    float* posx4   = ws + alloc((size_t)N * 4);
    float* radii   = ws + alloc(N);
    float* e_iw    = ws + alloc(N);
    float* e_ow    = ws + alloc(N);
    float* rowinv  = ws + alloc(N);
    float* scal    = ws + alloc(4);
    float* outPart = ws + alloc((size_t)OB * OUT_DIM * 64);
    float* fn      = ws + alloc((size_t)N * FD);
    float* actA    = ws + alloc((size_t)N * 64);
    float* actB    = ws + alloc((size_t)N * 64);
    float* nbr_w   = ws + alloc((size_t)N * MAXN);
    int*   nbr_idx = (int*)(ws + alloc((size_t)N * MAXN));
    int*   nbr_cnt = (int*)(ws + alloc(N));
    // partial act0 [KSPLIT][N][64] aliased onto nbr_w+nbr_idx (consumed before k_scan writes them)
    float* partial = nbr_w;   // KSPLIT*N*64 = 3.584M floats <= 2*N*MAXN = 5.12M floats

    hipMemsetAsync(scal, 0, 4 * sizeof(float), stream);

    k_pre<<<(N + 255) / 256, 256, 0, stream>>>(positions, radii_in, features,
                                               posx4, radii, e_iw, e_ow, fn, scal, N);
    k_xt<<<(B * IN + 255) / 256, 256, 0, stream>>>(x, xT, B, IN);
    k_act0<<<dim3(N / 32, KSPLIT), 256, 0, stream>>>(xT, Win, partial, N, IN);
    k_act0_red<<<(N * 64) / 256, 256, 0, stream>>>(partial, e_iw, scal, actA, N);
    k_scan<<<N / ITILE, 256, 0, stream>>>(posx4, scal, nbr_idx, nbr_w, nbr_cnt, N);
    k_weight<<<N, 128, 0, stream>>>(fn, radii, nbr_idx, nbr_w, nbr_cnt, rowinv, N);

    float* bufs[2] = {actA, actB};
    for (int it = 0; it < MAX_LAUNCH_ITERS; it++) {
        k_iter<<<N, 256, 0, stream>>>(bufs[it & 1], bufs[(it + 1) & 1],
                                      nbr_idx, nbr_w, nbr_cnt, rowinv, thr, nIter, it, N);
    }
    k_out1<<<OB, 256, 0, stream>>>(actA, actB, nIter, e_ow, scal, Wout, outPart, N);
    k_out2<<<3, 256, 0, stream>>>(outPart, (float*)d_out);
}

// Round 4
// 250.498 us; speedup vs baseline: 2.1223x; 1.1824x over previous
//
#include <hip/hip_runtime.h>
#include <hip/hip_bf16.h>
#include <math.h>

#define VOLF 100.0f
#define FD 32
#define OUT_DIM 10
#define MAXN 320
#define MAX_LAUNCH_ITERS 4
#define KSPLIT 7
#define BM 64      // neurons per block in k_act0
#define BKQ 28     // 112 k's / 4 per block-chunk
#define ITILE 8
#define OB 128     // k_out partial blocks

// ---------------- K1: per-neuron preprocess ----------------
__global__ __launch_bounds__(256) void k_pre(
    const float* __restrict__ positions, const float* __restrict__ radii_in,
    const float* __restrict__ features, float* __restrict__ posx4,
    float* __restrict__ radii, float* __restrict__ e_iw, float* __restrict__ e_ow,
    float* __restrict__ fn, float* __restrict__ scal, int N)
{
    int i = blockIdx.x * blockDim.x + threadIdx.x;
    float my_iw = 0.0f, my_ow = 0.0f, my_r = 0.0f;
    if (i < N) {
        float px = fminf(fmaxf(positions[3*i+0], 0.1f), VOLF - 0.1f);
        float py = fminf(fmaxf(positions[3*i+1], 0.1f), VOLF - 0.1f);
        float pz = fminf(fmaxf(positions[3*i+2], 0.1f), VOLF - 0.1f);
        float sq = px*px + py*py + pz*pz;
        posx4[4*i+0] = px; posx4[4*i+1] = py; posx4[4*i+2] = pz; posx4[4*i+3] = sq;
        float r = fminf(fmaxf(radii_in[i], 1.0f), 50.0f);
        radii[i] = r; my_r = r;
        float xc = fminf(fmaxf(px / VOLF, 0.0f), 1.0f);
        my_iw = expf(-3.0f * xc);
        my_ow = expf(3.0f * (xc - 1.0f));
        e_iw[i] = my_iw; e_ow[i] = my_ow;
        float s = 0.0f;
        #pragma unroll
        for (int k = 0; k < FD; k++) { float v = features[(size_t)i*FD + k]; s += v*v; }
        float nrm = fmaxf(sqrtf(s), 1e-6f);
        #pragma unroll
        for (int k = 0; k < FD; k++) fn[(size_t)i*FD + k] = features[(size_t)i*FD + k] / nrm;
    }
    __shared__ float red[256];
    red[threadIdx.x] = my_iw; __syncthreads();
    for (int s = 128; s > 0; s >>= 1) { if (threadIdx.x < s) red[threadIdx.x] += red[threadIdx.x + s]; __syncthreads(); }
    if (threadIdx.x == 0) atomicAdd(&scal[0], red[0]);
    __syncthreads();
    red[threadIdx.x] = my_ow; __syncthreads();
    for (int s = 128; s > 0; s >>= 1) { if (threadIdx.x < s) red[threadIdx.x] += red[threadIdx.x + s]; __syncthreads(); }
    if (threadIdx.x == 0) atomicAdd(&scal[1], red[0]);
    if (i < N) atomicMax((int*)&scal[2], __float_as_int(my_r));
}

// ---------------- K2: transpose x -> xT [IN][B] ----------------
__global__ __launch_bounds__(256) void k_xt(const float* __restrict__ x, float* __restrict__ xT,
                                            int B, int IN)
{
    int idx = blockIdx.x * blockDim.x + threadIdx.x;
    if (idx < B * IN) {
        int b = idx / IN, k = idx % IN;
        xT[(size_t)k * B + b] = x[idx];
    }
}

// ---------------- K3: LDS-tiled partial GEMM: partial[ks][N][64] ----------------
__global__ __launch_bounds__(256) void k_act0(
    const float* __restrict__ xT, const float* __restrict__ Wi,
    float* __restrict__ partial, int N, int IN)
{
    __shared__ float4 xs4[BKQ * 64];       // [kq][lane] = xT[k0+4kq..+3][lane]
    __shared__ float  wt[BM * 112];        // [row][k] row-major, 448B rows
    int t = threadIdx.x;
    int i0 = blockIdx.x * BM;
    int k0 = blockIdx.y * 112;
    // stage W tile: 64 rows x 112 floats, coalesced float4
    #pragma unroll
    for (int fi = t; fi < BM * 28; fi += 256) {
        int row = fi / 28, cq = fi % 28;
        ((float4*)wt)[row * 28 + cq] = *(const float4*)(Wi + (size_t)(i0 + row) * IN + k0 + cq * 4);
    }
    // stage xT chunk transposed into float4-per-lane
    {
        int l = t & 63, q = t >> 6;
        #pragma unroll
        for (int kq = q; kq < BKQ; kq += 4) {
            float4 v;
            v.x = xT[(size_t)(k0 + 4*kq + 0) * 64 + l];
            v.y = xT[(size_t)(k0 + 4*kq + 1) * 64 + l];
            v.z = xT[(size_t)(k0 + 4*kq + 2) * 64 + l];
            v.w = xT[(size_t)(k0 + 4*kq + 3) * 64 + l];
            xs4[kq * 64 + l] = v;
        }
    }
    __syncthreads();
    int wave = t >> 6, lane = t & 63;
    int nbase = wave * 16;
    float acc[16];
    #pragma unroll
    for (int n = 0; n < 16; n++) acc[n] = 0.0f;
    for (int kq = 0; kq < BKQ; kq++) {
        float4 xv = xs4[kq * 64 + lane];
        #pragma unroll
        for (int n = 0; n < 16; n++) {
            float4 w = ((const float4*)(wt + (nbase + n) * 112))[kq];
            acc[n] += w.x * xv.x + w.y * xv.y + w.z * xv.z + w.w * xv.w;
        }
    }
    size_t base = ((size_t)blockIdx.y * N + (i0 + nbase)) * 64 + lane;
    #pragma unroll
    for (int n = 0; n < 16; n++)
        partial[base + (size_t)n * 64] = acc[n];
}

// ---------------- K3b: reduce K-split partials, apply input gating ----------------
__global__ __launch_bounds__(256) void k_act0_red(
    const float* __restrict__ partial, const float* __restrict__ e_iw,
    const float* __restrict__ scal, float* __restrict__ actA, int N)
{
    int idx = blockIdx.x * 256 + threadIdx.x;   // over N*64
    int i = idx >> 6;
    size_t stride = (size_t)N * 64;
    float s = 0.0f;
    #pragma unroll
    for (int ks = 0; ks < KSPLIT; ks++) s += partial[ks * stride + idx];
    float inv = 1.0f / (scal[0] + 1e-6f);
    actA[idx] = s * (e_iw[i] * inv);
}

// ---------------- K4a: dense distance scan -> compacted (j, dist) ----------------
__global__ __launch_bounds__(256) void k_scan(
    const float* __restrict__ posx4, const float* __restrict__ scal,
    int* __restrict__ nbr_idx, float* __restrict__ nbr_w /* dist out */,
    int* __restrict__ nbr_cnt, int N)
{
    int i0 = blockIdx.x * ITILE;
    __shared__ int cnt[ITILE];
    if (threadIdx.x < ITILE) cnt[threadIdx.x] = 0;
    __syncthreads();
    float4 pi[ITILE];
    #pragma unroll
    for (int t = 0; t < ITILE; t++) pi[t] = ((const float4*)posx4)[i0 + t];
    float maxr = __int_as_float(((const int*)scal)[2]);
    for (int j = threadIdx.x; j < N; j += 256) {
        float4 pj = ((const float4*)posx4)[j];
        #pragma unroll
        for (int t = 0; t < ITILE; t++) {
            float d2 = fmaxf(pi[t].w + pj.w - 2.0f*(pi[t].x*pj.x + pi[t].y*pj.y + pi[t].z*pj.z), 0.0f);
            float dist = (d2 > 0.0f) ? sqrtf(d2) : 0.0f;
            if (dist < maxr) {
                int pos = atomicAdd(&cnt[t], 1);
                if (pos < MAXN) {
                    nbr_idx[(size_t)(i0+t) * MAXN + pos] = j;
                    nbr_w [(size_t)(i0+t) * MAXN + pos] = dist;
                }
            }
        }
    }
    __syncthreads();
    if (threadIdx.x < ITILE) nbr_cnt[i0 + threadIdx.x] = min(cnt[threadIdx.x], MAXN);
}

// ---------------- K4b: dense weight computation over compacted edges ----------------
__global__ __launch_bounds__(128) void k_weight(
    const float* __restrict__ fn, const float* __restrict__ radii,
    const int* __restrict__ nbr_idx, float* __restrict__ nbr_w /* in: dist, out: w */,
    const int* __restrict__ nbr_cnt, float* __restrict__ rowinv, int N)
{
    int i = blockIdx.x;
    __shared__ float4 fni[FD/4];
    __shared__ float red[128];
    if (threadIdx.x < FD/4) fni[threadIdx.x] = ((const float4*)(fn + (size_t)i * FD))[threadIdx.x];
    __syncthreads();
    float inv_ri = 1.0f / (radii[i] + 1e-6f);
    int cnt = nbr_cnt[i];
    float s = 0.0f;
    for (int e = threadIdx.x; e < cnt; e += 128) {
        int j     = nbr_idx[(size_t)i * MAXN + e];
        float dist= nbr_w [(size_t)i * MAXN + e];
        const float4* fnj = (const float4*)(fn + (size_t)j * FD);
        float fs = 0.0f;
        #pragma unroll
        for (int k = 0; k < FD/4; k++) {
            float4 a = fni[k], b = fnj[k];
            fs += a.x*b.x + a.y*b.y + a.z*b.z + a.w*b.w;
        }
        fs = fminf(fmaxf(fs, -1.0f), 1.0f);
        float w = expf(-fminf(dist * inv_ri, 20.0f)) * (0.3f + 0.7f * fs);
        nbr_w[(size_t)i * MAXN + e] = w;
        s += w;
    }
    red[threadIdx.x] = s; __syncthreads();
    for (int st = 64; st > 0; st >>= 1) { if (threadIdx.x < st) red[threadIdx.x] += red[threadIdx.x + st]; __syncthreads(); }
    if (threadIdx.x == 0) rowinv[i] = 1.0f / (red[0] + 1e-6f);
}

// ---------------- K5: one iteration (sparse matvec over 64 batches) ----------------
__global__ __launch_bounds__(256) void k_iter(
    const float* __restrict__ actIn, float* __restrict__ actOut,
    const int* __restrict__ nbr_idx, const float* __restrict__ nbr_w,
    const int* __restrict__ nbr_cnt, const float* __restrict__ rowinv,
    const float* __restrict__ thr,
    const int* __restrict__ nIterPtr, int iterIdx, int N)
{
    if (iterIdx >= min(*nIterPtr, MAX_LAUNCH_ITERS)) return;   // inactive launch: no-op
    int i = blockIdx.x;
    int wave = threadIdx.x >> 6, lane = threadIdx.x & 63;
    int cnt = nbr_cnt[i];
    float acc = 0.0f;
    for (int e = wave; e < cnt; e += 4) {
        int j   = nbr_idx[(size_t)i * MAXN + e];
        float w = nbr_w [(size_t)i * MAXN + e];
        acc += actIn[(size_t)j * 64 + lane] * w;
    }
    __shared__ float redA[4 * 64];
    redA[wave * 64 + lane] = acc;
    __syncthreads();
    if (wave == 0) {
        float tot = redA[lane] + redA[64 + lane] + redA[128 + lane] + redA[192 + lane];
        float v = actIn[(size_t)i * 64 + lane] + tot * rowinv[i] - thr[i];
        v = fminf(fmaxf(v, 0.0f), 100.0f);
        actOut[(size_t)i * 64 + lane] = v;
    }
}

// ---------------- K6a: output projection partials ----------------
__global__ __launch_bounds__(256) void k_out1(
    const float* __restrict__ actA, const float* __restrict__ actB,
    const int* __restrict__ nIterPtr, const float* __restrict__ e_ow,
    const float* __restrict__ scal, const float* __restrict__ outW,
    float* __restrict__ outPart, int N)
{
    int m = min(*nIterPtr, MAX_LAUNCH_ITERS);
    const float* actF = (m & 1) ? actB : actA;
    int wave = threadIdx.x >> 6, lane = threadIdx.x & 63;
    float inv = 1.0f / (scal[1] + 1e-6f);
    float acc[OUT_DIM];
    #pragma unroll
    for (int o = 0; o < OUT_DIM; o++) acc[o] = 0.0f;
    for (int i = blockIdx.x * 4 + wave; i < N; i += OB * 4) {
        float a = actF[(size_t)i * 64 + lane] * (e_ow[i] * inv);
        const float* wo = outW + (size_t)i * OUT_DIM;
        #pragma unroll
        for (int o = 0; o < OUT_DIM; o++) acc[o] += a * wo[o];
    }
    __shared__ float red[4][OUT_DIM][64];
    #pragma unroll
    for (int o = 0; o < OUT_DIM; o++) red[wave][o][lane] = acc[o];
    __syncthreads();
    if (wave == 0) {
        #pragma unroll
        for (int o = 0; o < OUT_DIM; o++) {
            float s = red[0][o][lane] + red[1][o][lane] + red[2][o][lane] + red[3][o][lane];
            outPart[((size_t)blockIdx.x * OUT_DIM + o) * 64 + lane] = s;
        }
    }
}

// ---------------- K6b: reduce partials -> out[b*10+o] ----------------
__global__ __launch_bounds__(256) void k_out2(
    const float* __restrict__ outPart, float* __restrict__ out)
{
    int t = blockIdx.x * 256 + threadIdx.x;     // over 640
    if (t >= 64 * OUT_DIM) return;
    int b = t / OUT_DIM, o = t % OUT_DIM;
    float s = 0.0f;
    for (int blk = 0; blk < OB; blk++)
        s += outPart[((size_t)blk * OUT_DIM + o) * 64 + b];
    out[t] = s;
}

extern "C" void kernel_launch(void* const* d_in, const int* in_sizes, int n_in,
                              void* d_out, int out_size, void* d_ws, size_t ws_size,
                              hipStream_t stream)
{
    const float* x        = (const float*)d_in[0];
    const float* positions= (const float*)d_in[1];
    const float* Win      = (const float*)d_in[2];
    const float* features = (const float*)d_in[3];
    const float* Wout     = (const float*)d_in[4];
    const float* radii_in = (const float*)d_in[5];
    const float* thr      = (const float*)d_in[6];
    const int*   nIter    = (const int*)  d_in[7];

    const int N  = in_sizes[5];            // 8000
    const int IN = in_sizes[2] / N;        // 784
    const int B  = in_sizes[0] / IN;       // 64 (kernels assume 64 = wave size)
    (void)B;

    float* ws = (float*)d_ws;
    size_t off = 0;
    auto alloc = [&](size_t nfloats) { size_t cur = off; off += (nfloats + 63) & ~(size_t)63; return cur; };
    float* xT      = ws + alloc((size_t)B * IN);
    float* posx4   = ws + alloc((size_t)N * 4);
    float* radii   = ws + alloc(N);
    float* e_iw    = ws + alloc(N);
    float* e_ow    = ws + alloc(N);
    float* rowinv  = ws + alloc(N);
    float* scal    = ws + alloc(4);
    float* outPart = ws + alloc((size_t)OB * OUT_DIM * 64);
    float* fn      = ws + alloc((size_t)N * FD);
    float* actA    = ws + alloc((size_t)N * 64);
    float* actB    = ws + alloc((size_t)N * 64);
    float* nbr_w   = ws + alloc((size_t)N * MAXN);
    int*   nbr_idx = (int*)(ws + alloc((size_t)N * MAXN));
    int*   nbr_cnt = (int*)(ws + alloc(N));
    // partial act0 [KSPLIT][N][64] aliased onto nbr_w+nbr_idx (consumed before k_scan writes them)
    float* partial = nbr_w;   // KSPLIT*N*64 = 3.584M floats <= 2*N*MAXN = 5.12M floats

    hipMemsetAsync(scal, 0, 4 * sizeof(float), stream);

    k_pre<<<(N + 255) / 256, 256, 0, stream>>>(positions, radii_in, features,
                                               posx4, radii, e_iw, e_ow, fn, scal, N);
    k_xt<<<(B * IN + 255) / 256, 256, 0, stream>>>(x, xT, B, IN);
    k_act0<<<dim3(N / BM, KSPLIT), 256, 0, stream>>>(xT, Win, partial, N, IN);
    k_act0_red<<<(N * 64) / 256, 256, 0, stream>>>(partial, e_iw, scal, actA, N);
    k_scan<<<N / ITILE, 256, 0, stream>>>(posx4, scal, nbr_idx, nbr_w, nbr_cnt, N);
    k_weight<<<N, 128, 0, stream>>>(fn, radii, nbr_idx, nbr_w, nbr_cnt, rowinv, N);

    float* bufs[2] = {actA, actB};
    for (int it = 0; it < MAX_LAUNCH_ITERS; it++) {
        k_iter<<<N, 256, 0, stream>>>(bufs[it & 1], bufs[(it + 1) & 1],
                                      nbr_idx, nbr_w, nbr_cnt, rowinv, thr, nIter, it, N);
    }
    k_out1<<<OB, 256, 0, stream>>>(actA, actB, nIter, e_ow, scal, Wout, outPart, N);
    k_out2<<<3, 256, 0, stream>>>(outPart, (float*)d_out);
}